// Round 1
// baseline (2503.690 us; speedup 1.0000x reference)
//
#include <hip/hip_runtime.h>
#include <math.h>

#define NB 256
#define NS 64
#define NH 128
#define NZ 128
#define NSTEPS 63

// Dynamic LDS overlay. preA/preP rows padded to 129 floats: in the tanh-dot
// phases bank = (s + j) % 32 -> 2-way aliasing only (free on gfx950, m136).
struct SM {
  float preA[NS * 129];   // IH @ W_a[:H]   per-b, computed once
  float preP[NS * 129];   // IH @ Wp[:H]    per-b, computed once
  float h[NH];
  float refh[NH];
  float gi[3 * NH];
  float gh[3 * NH];
  float atth[NH];
  float ctx[NH];
  float fc1[2 * NH];
  float fco[NH];
  float ptrh[NH];
  float zw1[2 * NH];      // Z @ W1[H:H+ZD] per-b, computed once
  float attn[NS];
  float maskv[NS];
  float red[256];
  float refin[2];
};

// Transpose [W_ih; W_hh] (768 x 128, row-major, @W^T form) into WT[k*768 + o]
// so the per-step matvec reads are coalesced in the output index o.
__global__ void prep_kernel(const float* __restrict__ W_ih,
                            const float* __restrict__ W_hh,
                            float* __restrict__ WT) {
  int idx = blockIdx.x * blockDim.x + threadIdx.x;
  if (idx >= 128 * 768) return;
  int k = idx / 768, o = idx % 768;
  WT[idx] = (o < 384) ? W_ih[o * 128 + k] : W_hh[(o - 384) * 128 + k];
}

template <bool USE_T>
__global__ __launch_bounds__(256) void decoder_kernel(
    const float* __restrict__ instance, const int* __restrict__ solution,
    const float* __restrict__ Z, const float* __restrict__ IH,
    const float* __restrict__ last_hh, const float* __restrict__ W_emb,
    const float* __restrict__ b_emb, const float* __restrict__ W_ih,
    const float* __restrict__ W_hh, const float* __restrict__ b_ih,
    const float* __restrict__ b_hh, const float* __restrict__ W_a,
    const float* __restrict__ v_a, const float* __restrict__ W1,
    const float* __restrict__ b1, const float* __restrict__ W2,
    const float* __restrict__ b2, const float* __restrict__ Wp,
    const float* __restrict__ vp, const float* __restrict__ WT,
    float* __restrict__ out) {
  extern __shared__ float smraw[];
  SM& sm = *reinterpret_cast<SM*>(smraw);
  const int b = blockIdx.x;
  const int t = threadIdx.x;
  const float* ihb = IH + b * NS * NH;

  // ---------------- startup (once per block) ----------------
  if (t < NS) sm.maskv[t] = 1.0f;
  if (t < NH) sm.h[t] = last_hh[b * NH + t];
  __syncthreads();
  if (t == 0) {
    int s0 = solution[b * NS];
    sm.maskv[s0] = 0.0f;
    sm.refin[0] = instance[(b * NS + s0) * 2 + 0];
    sm.refin[1] = instance[(b * NS + s0) * 2 + 1];
    out[b * NS] = (float)s0;  // tour_idx[:,0] = solution[:,0]
  }
  // zw1[t] = sum_k Z[b,k] * W1[H+k, t]   (t = 0..255)
  {
    const float* zb = Z + b * NZ;
    float a0 = 0.f, a1 = 0.f, a2 = 0.f, a3 = 0.f;
#pragma unroll 4
    for (int k = 0; k < NZ; k += 4) {
      a0 += zb[k + 0] * W1[(NH + k + 0) * 256 + t];
      a1 += zb[k + 1] * W1[(NH + k + 1) * 256 + t];
      a2 += zb[k + 2] * W1[(NH + k + 2) * 256 + t];
      a3 += zb[k + 3] * W1[(NH + k + 3) * 256 + t];
    }
    sm.zw1[t] = a0 + a1 + a2 + a3;
  }
  // preA[s,j] = sum_k IH[b,s,k]*W_a[k,j];  preP[s,j] = sum_k IH[b,s,k]*Wp[k,j]
  for (int o = t; o < NS * NH; o += 256) {
    int s = o >> 7, j = o & 127;
    const float* row = ihb + s * NH;
    float a0 = 0.f, a1 = 0.f, a2 = 0.f, a3 = 0.f;
    float p0 = 0.f, p1 = 0.f, p2 = 0.f, p3 = 0.f;
#pragma unroll 4
    for (int k = 0; k < NH; k += 4) {
      float r0 = row[k], r1 = row[k + 1], r2 = row[k + 2], r3 = row[k + 3];
      a0 += r0 * W_a[(k + 0) * NH + j];
      a1 += r1 * W_a[(k + 1) * NH + j];
      a2 += r2 * W_a[(k + 2) * NH + j];
      a3 += r3 * W_a[(k + 3) * NH + j];
      p0 += r0 * Wp[(k + 0) * NH + j];
      p1 += r1 * Wp[(k + 1) * NH + j];
      p2 += r2 * Wp[(k + 2) * NH + j];
      p3 += r3 * Wp[(k + 3) * NH + j];
    }
    sm.preA[s * 129 + j] = a0 + a1 + a2 + a3;
    sm.preP[s * 129 + j] = p0 + p1 + p2 + p3;
  }

  // ---------------- 63 sequential decode steps ----------------
  for (int step = 1; step <= NSTEPS; ++step) {
    __syncthreads();  // startup / previous phase-H writes visible
    // phase 0: ref_h = ref_in @ W_emb + b_emb  (IN = 2)
    if (t < NH)
      sm.refh[t] = sm.refin[0] * W_emb[t] + sm.refin[1] * W_emb[NH + t] + b_emb[t];
    __syncthreads();
    // phase A: gi = refh@W_ih^T + b_ih, gh = h@W_hh^T + b_hh  (768 dots of 128)
    {
      float a0 = 0.f, a1 = 0.f, a2 = 0.f;
      const int o0 = t, o1 = t + 256, o2 = t + 512;
      const bool lo = (t < 128);
#pragma unroll 4
      for (int k = 0; k < NH; ++k) {
        float rv = sm.refh[k], hv = sm.h[k];
        float x1 = lo ? rv : hv;
        float w0, w1, w2;
        if (USE_T) {
          const float* rw = WT + k * 768;
          w0 = rw[o0]; w1 = rw[o1]; w2 = rw[o2];
        } else {
          w0 = W_ih[o0 * NH + k];
          w1 = (o1 < 384) ? W_ih[o1 * NH + k] : W_hh[(o1 - 384) * NH + k];
          w2 = W_hh[(o2 - 384) * NH + k];
        }
        a0 += rv * w0; a1 += x1 * w1; a2 += hv * w2;
      }
      sm.gi[t] = a0 + b_ih[t];
      if (t < 128) sm.gi[256 + t] = a1 + b_ih[256 + t];
      else         sm.gh[t - 128] = a1 + b_hh[t - 128];
      sm.gh[t + 128] = a2 + b_hh[t + 128];
    }
    __syncthreads();
    // GRU gates
    if (t < NH) {
      float r = 1.f / (1.f + expf(-(sm.gi[t] + sm.gh[t])));
      float z = 1.f / (1.f + expf(-(sm.gi[NH + t] + sm.gh[NH + t])));
      float n = tanhf(sm.gi[2 * NH + t] + r * sm.gh[2 * NH + t]);
      sm.h[t] = (1.f - z) * n + z * sm.h[t];
    }
    __syncthreads();
    // phase B: atth[t] = sum_k h[k] * W_a[H+k, t]
    if (t < NH) {
      float a0 = 0.f, a1 = 0.f, a2 = 0.f, a3 = 0.f;
#pragma unroll 4
      for (int k = 0; k < NH; k += 4) {
        a0 += sm.h[k + 0] * W_a[(NH + k + 0) * NH + t];
        a1 += sm.h[k + 1] * W_a[(NH + k + 1) * NH + t];
        a2 += sm.h[k + 2] * W_a[(NH + k + 2) * NH + t];
        a3 += sm.h[k + 3] * W_a[(NH + k + 3) * NH + t];
      }
      sm.atth[t] = a0 + a1 + a2 + a3;
    }
    __syncthreads();
    // phase C: attention score partials (2 threads per s)
    if (t < 128) {
      int s = t >> 1, q = t & 1;
      const float* pa = sm.preA + s * 129 + q * 64;
      const float* ah = sm.atth + q * 64;
      const float* va = v_a + q * 64;
      float acc = 0.f;
#pragma unroll 4
      for (int j = 0; j < 64; ++j) acc += tanhf(pa[j] + ah[j]) * va[j];
      sm.red[t] = acc;
    }
    __syncthreads();
    // softmax over s (single wave)
    if (t < NS) {
      float e = sm.red[2 * t] + sm.red[2 * t + 1];
      float m = e;
#pragma unroll
      for (int off = 32; off > 0; off >>= 1) m = fmaxf(m, __shfl_xor(m, off));
      float p = expf(e - m);
      float ssum = p;
#pragma unroll
      for (int off = 32; off > 0; off >>= 1) ssum += __shfl_xor(ssum, off);
      sm.attn[t] = p / ssum;
    }
    __syncthreads();
    // phase D: context[t] = sum_s attn[s] * IH[b,s,t]
    if (t < NH) {
      float a0 = 0.f, a1 = 0.f, a2 = 0.f, a3 = 0.f;
#pragma unroll 4
      for (int s = 0; s < NS; s += 4) {
        a0 += sm.attn[s + 0] * ihb[(s + 0) * NH + t];
        a1 += sm.attn[s + 1] * ihb[(s + 1) * NH + t];
        a2 += sm.attn[s + 2] * ihb[(s + 2) * NH + t];
        a3 += sm.attn[s + 3] * ihb[(s + 3) * NH + t];
      }
      sm.ctx[t] = a0 + a1 + a2 + a3;
    }
    __syncthreads();
    // phase E1: fc1[t] = ctx@W1[:H] + zw1 + refh@W1[2H:3H] + b1
    {
      float a0 = 0.f, a1 = 0.f, c0 = 0.f, c1 = 0.f;
#pragma unroll 4
      for (int k = 0; k < NH; k += 2) {
        a0 += sm.ctx[k + 0] * W1[(k + 0) * 256 + t];
        a1 += sm.ctx[k + 1] * W1[(k + 1) * 256 + t];
        c0 += sm.refh[k + 0] * W1[(256 + k + 0) * 256 + t];
        c1 += sm.refh[k + 1] * W1[(256 + k + 1) * 256 + t];
      }
      sm.fc1[t] = a0 + a1 + c0 + c1 + sm.zw1[t] + b1[t];
    }
    __syncthreads();
    // phase E2: fco[t] = fc1 @ W2 + b2
    if (t < NH) {
      float a0 = 0.f, a1 = 0.f, a2 = 0.f, a3 = 0.f;
#pragma unroll 4
      for (int k = 0; k < 256; k += 4) {
        a0 += sm.fc1[k + 0] * W2[(k + 0) * NH + t];
        a1 += sm.fc1[k + 1] * W2[(k + 1) * NH + t];
        a2 += sm.fc1[k + 2] * W2[(k + 2) * NH + t];
        a3 += sm.fc1[k + 3] * W2[(k + 3) * NH + t];
      }
      sm.fco[t] = a0 + a1 + a2 + a3 + b2[t];
    }
    __syncthreads();
    // phase F: ptrh[t] = sum_k fco[k] * Wp[H+k, t]
    if (t < NH) {
      float a0 = 0.f, a1 = 0.f, a2 = 0.f, a3 = 0.f;
#pragma unroll 4
      for (int k = 0; k < NH; k += 4) {
        a0 += sm.fco[k + 0] * Wp[(NH + k + 0) * NH + t];
        a1 += sm.fco[k + 1] * Wp[(NH + k + 1) * NH + t];
        a2 += sm.fco[k + 2] * Wp[(NH + k + 2) * NH + t];
        a3 += sm.fco[k + 3] * Wp[(NH + k + 3) * NH + t];
      }
      sm.ptrh[t] = a0 + a1 + a2 + a3;
    }
    __syncthreads();
    // phase G: pointer logit partials
    if (t < 128) {
      int s = t >> 1, q = t & 1;
      const float* pp = sm.preP + s * 129 + q * 64;
      const float* ph = sm.ptrh + q * 64;
      const float* vv = vp + q * 64;
      float acc = 0.f;
#pragma unroll 4
      for (int j = 0; j < 64; ++j) acc += tanhf(pp[j] + ph[j]) * vv[j];
      sm.red[t] = acc;
    }
    __syncthreads();
    // phase H: masked log-softmax, argmax (JAX tie: first index), outputs
    if (t < NS) {
      float lg = sm.red[2 * t] + sm.red[2 * t + 1];
      float ml = (sm.maskv[t] > 0.5f) ? lg : -INFINITY;
      float m = ml; int mi = t;
#pragma unroll
      for (int off = 32; off > 0; off >>= 1) {
        float om = __shfl_xor(m, off);
        int oi = __shfl_xor(mi, off);
        if (om > m || (om == m && oi < mi)) { m = om; mi = oi; }
      }
      float p = expf(ml - m);  // masked lanes: exp(-inf) = 0
      float ssum = p;
#pragma unroll
      for (int off = 32; off > 0; off >>= 1) ssum += __shfl_xor(ssum, off);
      int ptr = solution[b * NS + step];
      float pv = __shfl(ml, ptr);
      if (t == 0) {
        out[b * NS + step] = (float)mi;
        out[NB * NS + b * NSTEPS + (step - 1)] = pv - m - logf(ssum);
        sm.maskv[ptr] = 0.0f;
        sm.refin[0] = instance[(b * NS + ptr) * 2 + 0];
        sm.refin[1] = instance[(b * NS + ptr) * 2 + 1];
      }
    }
  }
}

extern "C" void kernel_launch(void* const* d_in, const int* in_sizes, int n_in,
                              void* d_out, int out_size, void* d_ws,
                              size_t ws_size, hipStream_t stream) {
  (void)in_sizes; (void)n_in; (void)out_size;
  const float* instance = (const float*)d_in[0];
  const int*   solution = (const int*)d_in[1];
  const float* Z        = (const float*)d_in[2];
  const float* IH       = (const float*)d_in[3];
  const float* last_hh  = (const float*)d_in[4];
  const float* W_emb    = (const float*)d_in[5];
  const float* b_emb    = (const float*)d_in[6];
  const float* W_ih     = (const float*)d_in[7];
  const float* W_hh     = (const float*)d_in[8];
  const float* b_ih     = (const float*)d_in[9];
  const float* b_hh     = (const float*)d_in[10];
  const float* W_a      = (const float*)d_in[11];
  const float* v_a      = (const float*)d_in[12];
  const float* W1       = (const float*)d_in[13];
  const float* b1       = (const float*)d_in[14];
  const float* W2       = (const float*)d_in[15];
  const float* b2       = (const float*)d_in[16];
  const float* Wp       = (const float*)d_in[17];
  const float* vp       = (const float*)d_in[18];
  float* out = (float*)d_out;
  float* WT = (float*)d_ws;

  static_assert(sizeof(SM) <= 86016, "LDS overlay too big");
  const size_t shmem = 86016;  // > 80 KiB forces 1 block/CU (LDS 160 KiB)
  const bool use_t = (ws_size >= (size_t)(128 * 768 * sizeof(float)));

  if (use_t) {
    prep_kernel<<<(128 * 768 + 255) / 256, 256, 0, stream>>>(W_ih, W_hh, WT);
    hipFuncSetAttribute((const void*)decoder_kernel<true>,
                        hipFuncAttributeMaxDynamicSharedMemorySize, (int)shmem);
    decoder_kernel<true><<<NB, 256, shmem, stream>>>(
        instance, solution, Z, IH, last_hh, W_emb, b_emb, W_ih, W_hh, b_ih,
        b_hh, W_a, v_a, W1, b1, W2, b2, Wp, vp, WT, out);
  } else {
    hipFuncSetAttribute((const void*)decoder_kernel<false>,
                        hipFuncAttributeMaxDynamicSharedMemorySize, (int)shmem);
    decoder_kernel<false><<<NB, 256, shmem, stream>>>(
        instance, solution, Z, IH, last_hh, W_emb, b_emb, W_ih, W_hh, b_ih,
        b_hh, W_a, v_a, W1, b1, W2, b2, Wp, vp, WT, out);
  }
}

// Round 2
// 1621.207 us; speedup vs baseline: 1.5443x; 1.5443x over previous
//
#include <hip/hip_runtime.h>
#include <math.h>

#define NB 256
#define NS 64
#define NH 128
#define NZ 128
#define NSTEPS 63
#define PITCH 132  // preA/preP row pitch: 16B-aligned, 4-way bank alias max

struct SM {
  float preA[NS * PITCH];  // IH @ W_a[:H]   (per-b)
  float preP[NS * PITCH];  // IH @ Wp[:H]    (per-b)
  float Wa2[NH * NH];      // W_a[H+k][o] = Wa2[k*128+o]  (shared weights)
  float h[NH];
  float atth[NH];
  float ctx[NH];
  float fc1[2 * NH];
  float fco[NH];
  float ptrh[NH];
  float zw1[2 * NH];       // Z @ W1[H:H+ZD] (per-b)
  float Gpre[3 * 384];     // [W_emb;b_emb] @ W_ih^T (+b_ih)
  float E1ref[3 * 256];    // [W_emb;b_emb] @ W1[2H:3H] (+b1)
  float bhh[384];
  float b2s[NH];
  float va[NH];
  float vpv[NH];
  float attn[NS];
  float maskv[NS];
  float red[2048];         // generic partial-reduction scratch
  float refin[4];
};

__global__ __launch_bounds__(512, 2) void decoder_kernel(
    const float* __restrict__ instance, const int* __restrict__ solution,
    const float* __restrict__ Z, const float* __restrict__ IH,
    const float* __restrict__ last_hh, const float* __restrict__ W_emb,
    const float* __restrict__ b_emb, const float* __restrict__ W_ih,
    const float* __restrict__ W_hh, const float* __restrict__ b_ih,
    const float* __restrict__ b_hh, const float* __restrict__ W_a,
    const float* __restrict__ v_a, const float* __restrict__ W1,
    const float* __restrict__ b1, const float* __restrict__ W2,
    const float* __restrict__ b2, const float* __restrict__ Wp,
    const float* __restrict__ vp, float* __restrict__ out) {
  extern __shared__ float smraw[];
  SM& sm = *reinterpret_cast<SM*>(smraw);
  const int b = blockIdx.x;
  const int t = threadIdx.x;
  const float* ihb = IH + b * NS * NH;

  // ---------- thread-role constants ----------
  const int oA = t & 127, qA = t >> 7;        // phase A: 128 outs x 4 k-chunks
  const int ob = (t & 31) * 4, qB = t >> 5;   // quad-out x 16 chunks (B,D,E2,F)
  const int oE1 = (t & 63) * 4, qE1 = t >> 6; // quad-out x 8 chunks (E1)
  const int sC = t >> 3, qC = t & 7;          // tanh phases C,G

  // ---------- persistent register-cached weights ----------
  float4 whr[8], whz[8], whn[8];  // W_hh rows (r,z,n gate) k-chunk [32qA,32qA+32)
  {
    const float* br = W_hh + (0 * NH + oA) * NH + 32 * qA;
    const float* bz = W_hh + (1 * NH + oA) * NH + 32 * qA;
    const float* bn = W_hh + (2 * NH + oA) * NH + 32 * qA;
#pragma unroll
    for (int j4 = 0; j4 < 8; ++j4) {
      whr[j4] = *(const float4*)(br + 4 * j4);
      whz[j4] = *(const float4*)(bz + 4 * j4);
      whn[j4] = *(const float4*)(bn + 4 * j4);
    }
  }
  float4 w1c[16];  // W1[:H] ctx slice: rows 16qE1..+16, cols oE1..+4
  {
#pragma unroll
    for (int kk = 0; kk < 16; ++kk)
      w1c[kk] = *(const float4*)(W1 + (16 * qE1 + kk) * 256 + oE1);
  }

  // ---------- startup: fill LDS ----------
  if (t < NS) sm.maskv[t] = 1.0f;
  if (t < NH) {
    sm.h[t] = last_hh[b * NH + t];
    sm.b2s[t] = b2[t];
    sm.va[t] = v_a[t];
    sm.vpv[t] = vp[t];
  }
  if (t < 384) sm.bhh[t] = b_hh[t];
  for (int i = 4 * t; i < NH * NH; i += 2048)
    *(float4*)(sm.Wa2 + i) = *(const float4*)(W_a + NH * NH + i);
  // zw1[o] = Z[b] . W1[H:H+ZD, o]
  if (t < 256) {
    const float* zb = Z + b * NZ;
    float a0 = 0.f, a1 = 0.f;
#pragma unroll 4
    for (int k = 0; k < NZ; k += 2) {
      a0 += zb[k] * W1[(NH + k) * 256 + t];
      a1 += zb[k + 1] * W1[(NH + k + 1) * 256 + t];
    }
    sm.zw1[t] = a0 + a1;
  }
  // Gpre[c][o3] = [W_emb;b_emb][c] . W_ih[o3,:]  (+ b_ih for c=2)
  if (t < 384) {
    const float* wi = W_ih + t * NH;
    float g0 = 0.f, g1 = 0.f, g2 = 0.f;
#pragma unroll 4
    for (int k4 = 0; k4 < 32; ++k4) {
      float4 w = *(const float4*)(wi + 4 * k4);
      float4 e0 = *(const float4*)(W_emb + 4 * k4);
      float4 e1 = *(const float4*)(W_emb + NH + 4 * k4);
      float4 eb = *(const float4*)(b_emb + 4 * k4);
      g0 += w.x * e0.x + w.y * e0.y + w.z * e0.z + w.w * e0.w;
      g1 += w.x * e1.x + w.y * e1.y + w.z * e1.z + w.w * e1.w;
      g2 += w.x * eb.x + w.y * eb.y + w.z * eb.z + w.w * eb.w;
    }
    sm.Gpre[t] = g0;
    sm.Gpre[384 + t] = g1;
    sm.Gpre[768 + t] = g2 + b_ih[t];
  }
  // E1ref[c][o] = [W_emb;b_emb][c] . W1[2H+k, o]  (+ b1 for c=2)
  if (t < 256) {
    float e0 = 0.f, e1 = 0.f, e2 = 0.f;
#pragma unroll 4
    for (int k = 0; k < NH; ++k) {
      float w = W1[(256 + k) * 256 + t];
      e0 += W_emb[k] * w;
      e1 += W_emb[NH + k] * w;
      e2 += b_emb[k] * w;
    }
    sm.E1ref[t] = e0;
    sm.E1ref[256 + t] = e1;
    sm.E1ref[512 + t] = e2 + b1[t];
  }
  // preA / preP
  for (int o = t; o < NS * NH; o += 512) {
    int s = o >> 7, j = o & 127;
    const float* row = ihb + s * NH;
    float a0 = 0.f, a1 = 0.f, p0 = 0.f, p1 = 0.f;
#pragma unroll 4
    for (int k = 0; k < NH; k += 2) {
      float r0 = row[k], r1 = row[k + 1];
      a0 += r0 * W_a[k * NH + j];
      a1 += r1 * W_a[(k + 1) * NH + j];
      p0 += r0 * Wp[k * NH + j];
      p1 += r1 * Wp[(k + 1) * NH + j];
    }
    sm.preA[s * PITCH + j] = a0 + a1;
    sm.preP[s * PITCH + j] = p0 + p1;
  }
  __syncthreads();
  if (t == 0) {
    int s0 = solution[b * NS];
    sm.maskv[s0] = 0.0f;
    sm.refin[0] = instance[(b * NS + s0) * 2 + 0];
    sm.refin[1] = instance[(b * NS + s0) * 2 + 1];
    out[b * NS] = (float)s0;
  }

  // ---------- 63 sequential decode steps ----------
  for (int step = 1; step <= NSTEPS; ++step) {
    __syncthreads();
    // A: gh partials from register-cached W_hh (3 gates, k-chunk 32qA..+32)
    {
      float ar = 0.f, az = 0.f, an = 0.f;
      const float* hp = sm.h + 32 * qA;
#pragma unroll
      for (int j4 = 0; j4 < 8; ++j4) {
        float4 hv = *(const float4*)(hp + 4 * j4);
        ar += hv.x * whr[j4].x + hv.y * whr[j4].y + hv.z * whr[j4].z + hv.w * whr[j4].w;
        az += hv.x * whz[j4].x + hv.y * whz[j4].y + hv.z * whz[j4].z + hv.w * whz[j4].w;
        an += hv.x * whn[j4].x + hv.y * whn[j4].y + hv.z * whn[j4].z + hv.w * whn[j4].w;
      }
      sm.red[t] = ar;
      sm.red[512 + t] = az;
      sm.red[1024 + t] = an;
    }
    __syncthreads();
    // gates: combine partials + Gpre(refin) -> h
    if (t < NH) {
      float ghr = sm.red[t] + sm.red[t + 128] + sm.red[t + 256] + sm.red[t + 384] + sm.bhh[t];
      float ghz = sm.red[512 + t] + sm.red[512 + t + 128] + sm.red[512 + t + 256] + sm.red[512 + t + 384] + sm.bhh[NH + t];
      float ghn = sm.red[1024 + t] + sm.red[1024 + t + 128] + sm.red[1024 + t + 256] + sm.red[1024 + t + 384] + sm.bhh[2 * NH + t];
      float r0 = sm.refin[0], r1 = sm.refin[1];
      float gir = r0 * sm.Gpre[t] + r1 * sm.Gpre[384 + t] + sm.Gpre[768 + t];
      float giz = r0 * sm.Gpre[NH + t] + r1 * sm.Gpre[384 + NH + t] + sm.Gpre[768 + NH + t];
      float gin = r0 * sm.Gpre[2 * NH + t] + r1 * sm.Gpre[384 + 2 * NH + t] + sm.Gpre[768 + 2 * NH + t];
      float r = 1.f / (1.f + expf(-(gir + ghr)));
      float z = 1.f / (1.f + expf(-(giz + ghz)));
      float n = tanhf(gin + r * ghn);
      sm.h[t] = (1.f - z) * n + z * sm.h[t];
    }
    __syncthreads();
    // B: atth partials = h . Wa2 (LDS weights), quad-out x k-chunk 8
    {
      float4 acc = {0.f, 0.f, 0.f, 0.f};
      float4 h0 = *(const float4*)(sm.h + 8 * qB);
      float4 h1 = *(const float4*)(sm.h + 8 * qB + 4);
      float hk[8] = {h0.x, h0.y, h0.z, h0.w, h1.x, h1.y, h1.z, h1.w};
#pragma unroll
      for (int kk = 0; kk < 8; ++kk) {
        float4 w = *(const float4*)(sm.Wa2 + (8 * qB + kk) * NH + ob);
        acc.x += hk[kk] * w.x; acc.y += hk[kk] * w.y;
        acc.z += hk[kk] * w.z; acc.w += hk[kk] * w.w;
      }
      *(float4*)(sm.red + qB * NH + ob) = acc;
    }
    __syncthreads();
    if (t < NH) {  // Bsum
      float s = 0.f;
#pragma unroll
      for (int q = 0; q < 16; ++q) s += sm.red[q * NH + t];
      sm.atth[t] = s;
    }
    __syncthreads();
    // C: attention tanh-dot partials
    {
      const float* pa = sm.preA + sC * PITCH + 16 * qC;
      const float* ah = sm.atth + 16 * qC;
      const float* vv = sm.va + 16 * qC;
      float acc = 0.f;
#pragma unroll
      for (int u = 0; u < 4; ++u) {
        float4 a = *(const float4*)(pa + 4 * u);
        float4 hh = *(const float4*)(ah + 4 * u);
        float4 vw = *(const float4*)(vv + 4 * u);
        acc += tanhf(a.x + hh.x) * vw.x + tanhf(a.y + hh.y) * vw.y +
               tanhf(a.z + hh.z) * vw.z + tanhf(a.w + hh.w) * vw.w;
      }
      sm.red[t] = acc;  // t == sC*8 + qC
    }
    __syncthreads();
    // softmax over s (wave 0)
    if (t < NS) {
      float4 ra = *(const float4*)(sm.red + 8 * t);
      float4 rb = *(const float4*)(sm.red + 8 * t + 4);
      float e = ra.x + ra.y + ra.z + ra.w + rb.x + rb.y + rb.z + rb.w;
      float m = e;
#pragma unroll
      for (int off = 32; off > 0; off >>= 1) m = fmaxf(m, __shfl_xor(m, off));
      float p = expf(e - m);
      float ssum = p;
#pragma unroll
      for (int off = 32; off > 0; off >>= 1) ssum += __shfl_xor(ssum, off);
      sm.attn[t] = p / ssum;
    }
    __syncthreads();
    // D: context partials (IH streamed from L2), quad-out x s-chunk 4
    {
      float4 acc = {0.f, 0.f, 0.f, 0.f};
      const float* ib = ihb + (4 * qB) * NH + ob;
      float4 av = *(const float4*)(sm.attn + 4 * qB);
      float as[4] = {av.x, av.y, av.z, av.w};
#pragma unroll
      for (int ss = 0; ss < 4; ++ss) {
        float4 x = *(const float4*)(ib + ss * NH);
        acc.x += as[ss] * x.x; acc.y += as[ss] * x.y;
        acc.z += as[ss] * x.z; acc.w += as[ss] * x.w;
      }
      *(float4*)(sm.red + qB * NH + ob) = acc;
    }
    __syncthreads();
    if (t < NH) {  // Dsum
      float s = 0.f;
#pragma unroll
      for (int q = 0; q < 16; ++q) s += sm.red[q * NH + t];
      sm.ctx[t] = s;
    }
    __syncthreads();
    // E1: fc1 partials = ctx @ W1[:H] (register weights), quad-out x k-chunk 16
    {
      float4 acc = {0.f, 0.f, 0.f, 0.f};
#pragma unroll
      for (int k4 = 0; k4 < 4; ++k4) {
        float4 cv = *(const float4*)(sm.ctx + 16 * qE1 + 4 * k4);
        float cs[4] = {cv.x, cv.y, cv.z, cv.w};
#pragma unroll
        for (int u = 0; u < 4; ++u) {
          float4 w = w1c[4 * k4 + u];
          acc.x += cs[u] * w.x; acc.y += cs[u] * w.y;
          acc.z += cs[u] * w.z; acc.w += cs[u] * w.w;
        }
      }
      *(float4*)(sm.red + qE1 * 256 + oE1) = acc;
    }
    __syncthreads();
    if (t < 256) {  // E1sum (+ zw1 + refh@W1ref via E1ref)
      float s = 0.f;
#pragma unroll
      for (int q = 0; q < 8; ++q) s += sm.red[q * 256 + t];
      float r0 = sm.refin[0], r1 = sm.refin[1];
      sm.fc1[t] = s + sm.zw1[t] + r0 * sm.E1ref[t] + r1 * sm.E1ref[256 + t] + sm.E1ref[512 + t];
    }
    __syncthreads();
    // E2: fco partials = fc1 @ W2 (W2 streamed from L2), quad-out x k-chunk 16
    {
      float4 acc = {0.f, 0.f, 0.f, 0.f};
      const float* w2p = W2 + (16 * qB) * NH + ob;
#pragma unroll
      for (int k4 = 0; k4 < 4; ++k4) {
        float4 fv = *(const float4*)(sm.fc1 + 16 * qB + 4 * k4);
        float fs[4] = {fv.x, fv.y, fv.z, fv.w};
#pragma unroll
        for (int u = 0; u < 4; ++u) {
          float4 w = *(const float4*)(w2p + (4 * k4 + u) * NH);
          acc.x += fs[u] * w.x; acc.y += fs[u] * w.y;
          acc.z += fs[u] * w.z; acc.w += fs[u] * w.w;
        }
      }
      *(float4*)(sm.red + qB * NH + ob) = acc;
    }
    __syncthreads();
    if (t < NH) {  // E2sum
      float s = 0.f;
#pragma unroll
      for (int q = 0; q < 16; ++q) s += sm.red[q * NH + t];
      sm.fco[t] = s + sm.b2s[t];
    }
    __syncthreads();
    // F: ptrh partials = fco @ Wp[H:] (streamed from L2), quad-out x k-chunk 8
    {
      float4 acc = {0.f, 0.f, 0.f, 0.f};
      const float* wpp = Wp + (NH + 8 * qB) * NH + ob;
      float4 f0 = *(const float4*)(sm.fco + 8 * qB);
      float4 f1 = *(const float4*)(sm.fco + 8 * qB + 4);
      float fs[8] = {f0.x, f0.y, f0.z, f0.w, f1.x, f1.y, f1.z, f1.w};
#pragma unroll
      for (int kk = 0; kk < 8; ++kk) {
        float4 w = *(const float4*)(wpp + kk * NH);
        acc.x += fs[kk] * w.x; acc.y += fs[kk] * w.y;
        acc.z += fs[kk] * w.z; acc.w += fs[kk] * w.w;
      }
      *(float4*)(sm.red + qB * NH + ob) = acc;
    }
    __syncthreads();
    if (t < NH) {  // Fsum
      float s = 0.f;
#pragma unroll
      for (int q = 0; q < 16; ++q) s += sm.red[q * NH + t];
      sm.ptrh[t] = s;
    }
    __syncthreads();
    // G: pointer tanh-dot partials
    {
      const float* pp = sm.preP + sC * PITCH + 16 * qC;
      const float* ph = sm.ptrh + 16 * qC;
      const float* vv = sm.vpv + 16 * qC;
      float acc = 0.f;
#pragma unroll
      for (int u = 0; u < 4; ++u) {
        float4 a = *(const float4*)(pp + 4 * u);
        float4 hh = *(const float4*)(ph + 4 * u);
        float4 vw = *(const float4*)(vv + 4 * u);
        acc += tanhf(a.x + hh.x) * vw.x + tanhf(a.y + hh.y) * vw.y +
               tanhf(a.z + hh.z) * vw.z + tanhf(a.w + hh.w) * vw.w;
      }
      sm.red[t] = acc;
    }
    __syncthreads();
    // H: masked log-softmax, argmax (first-index tie), outputs, state update
    if (t < NS) {
      float4 ra = *(const float4*)(sm.red + 8 * t);
      float4 rb = *(const float4*)(sm.red + 8 * t + 4);
      float lg = ra.x + ra.y + ra.z + ra.w + rb.x + rb.y + rb.z + rb.w;
      float ml = (sm.maskv[t] > 0.5f) ? lg : -INFINITY;
      float m = ml;
      int mi = t;
#pragma unroll
      for (int off = 32; off > 0; off >>= 1) {
        float om = __shfl_xor(m, off);
        int oi = __shfl_xor(mi, off);
        if (om > m || (om == m && oi < mi)) { m = om; mi = oi; }
      }
      float p = expf(ml - m);
      float ssum = p;
#pragma unroll
      for (int off = 32; off > 0; off >>= 1) ssum += __shfl_xor(ssum, off);
      int ptr = solution[b * NS + step];
      float pv = __shfl(ml, ptr);
      if (t == 0) {
        out[b * NS + step] = (float)mi;
        out[NB * NS + b * NSTEPS + (step - 1)] = pv - m - logf(ssum);
        sm.maskv[ptr] = 0.0f;
        sm.refin[0] = instance[(b * NS + ptr) * 2 + 0];
        sm.refin[1] = instance[(b * NS + ptr) * 2 + 1];
      }
    }
  }
}

extern "C" void kernel_launch(void* const* d_in, const int* in_sizes, int n_in,
                              void* d_out, int out_size, void* d_ws,
                              size_t ws_size, hipStream_t stream) {
  (void)in_sizes; (void)n_in; (void)out_size; (void)d_ws; (void)ws_size;
  const float* instance = (const float*)d_in[0];
  const int*   solution = (const int*)d_in[1];
  const float* Z        = (const float*)d_in[2];
  const float* IH       = (const float*)d_in[3];
  const float* last_hh  = (const float*)d_in[4];
  const float* W_emb    = (const float*)d_in[5];
  const float* b_emb    = (const float*)d_in[6];
  const float* W_ih     = (const float*)d_in[7];
  const float* W_hh     = (const float*)d_in[8];
  const float* b_ih     = (const float*)d_in[9];
  const float* b_hh     = (const float*)d_in[10];
  const float* W_a      = (const float*)d_in[11];
  const float* v_a      = (const float*)d_in[12];
  const float* W1       = (const float*)d_in[13];
  const float* b1       = (const float*)d_in[14];
  const float* W2       = (const float*)d_in[15];
  const float* b2       = (const float*)d_in[16];
  const float* Wp       = (const float*)d_in[17];
  const float* vp       = (const float*)d_in[18];
  float* out = (float*)d_out;

  const int shmem = (int)sizeof(SM);
  static_assert(sizeof(SM) <= 160 * 1024, "LDS overlay too big");
  hipFuncSetAttribute((const void*)decoder_kernel,
                      hipFuncAttributeMaxDynamicSharedMemorySize, shmem);
  decoder_kernel<<<NB, 512, shmem, stream>>>(
      instance, solution, Z, IH, last_hh, W_emb, b_emb, W_ih, W_hh, b_ih, b_hh,
      W_a, v_a, W1, b1, W2, b2, Wp, vp, out);
}